// Round 1
// baseline (15436.708 us; speedup 1.0000x reference)
//
#include <hip/hip_runtime.h>

#define N_LINKS_C 10000
#define N_PATHS_C 131072
#define D_C 32
#define L_C 8
#define T_C 8
#define RU_C 256

__device__ __forceinline__ float sigm(float x){
  return __builtin_amdgcn_rcpf(1.0f + __expf(-x));
}
__device__ __forceinline__ float tanh_fast(float x){
  float e = __expf(2.0f*x);
  return 1.0f - 2.0f*__builtin_amdgcn_rcpf(e + 1.0f);
}

// ---------------------------------------------------------------------------
// Init: link_state[l] = [cap_l, 0...], path_state[p] = [bw_p, 0...]
// ---------------------------------------------------------------------------
__global__ __launch_bounds__(256) void init_states(
    const float* __restrict__ cap, const float* __restrict__ bw,
    float* __restrict__ link_state, float* __restrict__ path_state)
{
  const int i = blockIdx.x*256 + threadIdx.x;
  if (i < N_PATHS_C){
    float4* r = reinterpret_cast<float4*>(path_state + (size_t)i*D_C);
    float4 z = make_float4(0.f,0.f,0.f,0.f);
    float4 f = make_float4(bw[i],0.f,0.f,0.f);
    r[0]=f;
    #pragma unroll
    for (int q=1;q<8;q++) r[q]=z;
  }
  if (i < N_LINKS_C){
    float4* r = reinterpret_cast<float4*>(link_state + (size_t)i*D_C);
    float4 z = make_float4(0.f,0.f,0.f,0.f);
    float4 f = make_float4(cap[i],0.f,0.f,0.f);
    r[0]=f;
    #pragma unroll
    for (int q=1;q<8;q++) r[q]=z;
  }
}

// ---------------------------------------------------------------------------
// xw[l][j] = sum_i link_state[l][i]*path_kernel[i][j] + path_bias[0][j]
// one thread per (l,j); N_LINKS*96 = 960000 threads
// ---------------------------------------------------------------------------
__global__ __launch_bounds__(256) void precompute_xw(
    const float* __restrict__ link_state,
    const float* __restrict__ pk,
    const float* __restrict__ pbias,
    float* __restrict__ xw)
{
  const int tid = blockIdx.x*256 + threadIdx.x;
  if (tid >= N_LINKS_C*96) return;
  const int l = tid/96, j = tid - l*96;
  const float* x = link_state + (size_t)l*D_C;
  float acc = pbias[j];
  #pragma unroll
  for (int i=0;i<D_C;i++) acc = fmaf(x[i], pk[i*96+j], acc);
  xw[tid] = acc;
}

// ---------------------------------------------------------------------------
// Path GRU scan over L=8 links, fused with segment-sum (atomics) into m_link.
// One thread per path; recurrent weights transposed in LDS (broadcast reads).
// ---------------------------------------------------------------------------
__global__ __launch_bounds__(256) void path_step(
    const float* __restrict__ xw,       // [N_LINKS][96], bias0 folded in
    const int*   __restrict__ links,    // [N_PATHS*8]
    const float* __restrict__ prec,     // path_rec [32][96]
    const float* __restrict__ pbias,    // [2][96]
    float* __restrict__ path_state,     // [N_PATHS][32]
    float* __restrict__ m_link)         // [N_LINKS][32], pre-zeroed
{
  __shared__ float Rt[96*32];           // Rt[j][i] = prec[i][j]
  __shared__ float B1[96];
  for (int k = threadIdx.x; k < 96*32; k += 256)
    Rt[k] = prec[(k & 31)*96 + (k >> 5)];
  if (threadIdx.x < 96) B1[threadIdx.x] = pbias[96 + threadIdx.x];
  __syncthreads();

  const int p = blockIdx.x*256 + threadIdx.x;   // grid exactly covers N_PATHS
  float h[32];
  {
    const float4* ps4 = reinterpret_cast<const float4*>(path_state + (size_t)p*D_C);
    #pragma unroll
    for (int q=0;q<8;q++){ float4 v = ps4[q]; h[q*4]=v.x; h[q*4+1]=v.y; h[q*4+2]=v.z; h[q*4+3]=v.w; }
  }

  #pragma unroll 1
  for (int s=0;s<L_C;s++){
    const int l = links[p*8+s];
    const float* xr = xw + (size_t)l*96;
    float hn[32];
    #pragma unroll
    for (int d0=0; d0<32; d0+=4){
      const float4 xz4 = *reinterpret_cast<const float4*>(xr + d0);
      const float4 xr4 = *reinterpret_cast<const float4*>(xr + 32 + d0);
      const float4 xh4 = *reinterpret_cast<const float4*>(xr + 64 + d0);
      #pragma unroll
      for (int q=0;q<4;q++){
        const int d = d0+q;
        float hz = B1[d], hr = B1[32+d], hh = B1[64+d];
        const float4* rz = reinterpret_cast<const float4*>(Rt + d*32);
        const float4* rr = reinterpret_cast<const float4*>(Rt + (32+d)*32);
        const float4* rh = reinterpret_cast<const float4*>(Rt + (64+d)*32);
        #pragma unroll
        for (int i4=0;i4<8;i4++){
          const float4 a = rz[i4], b = rr[i4], c = rh[i4];
          hz = fmaf(a.x,h[i4*4+0],fmaf(a.y,h[i4*4+1],fmaf(a.z,h[i4*4+2],fmaf(a.w,h[i4*4+3],hz))));
          hr = fmaf(b.x,h[i4*4+0],fmaf(b.y,h[i4*4+1],fmaf(b.z,h[i4*4+2],fmaf(b.w,h[i4*4+3],hr))));
          hh = fmaf(c.x,h[i4*4+0],fmaf(c.y,h[i4*4+1],fmaf(c.z,h[i4*4+2],fmaf(c.w,h[i4*4+3],hh))));
        }
        const float xzv = (q==0)?xz4.x:(q==1)?xz4.y:(q==2)?xz4.z:xz4.w;
        const float xrv = (q==0)?xr4.x:(q==1)?xr4.y:(q==2)?xr4.z:xr4.w;
        const float xhv = (q==0)?xh4.x:(q==1)?xh4.y:(q==2)?xh4.z:xh4.w;
        const float z = sigm(xzv + hz);
        const float r = sigm(xrv + hr);
        const float c2 = tanh_fast(xhv + r*hh);
        hn[d] = z*h[d] + (1.0f - z)*c2;
      }
    }
    float* ml = m_link + (size_t)l*D_C;
    #pragma unroll
    for (int d=0; d<32; d++){ h[d]=hn[d]; atomicAdd(ml+d, h[d]); }
  }

  float4* ps4w = reinterpret_cast<float4*>(path_state + (size_t)p*D_C);
  #pragma unroll
  for (int q=0;q<8;q++){
    float4 v; v.x=h[q*4]; v.y=h[q*4+1]; v.z=h[q*4+2]; v.w=h[q*4+3];
    ps4w[q]=v;
  }
}

// ---------------------------------------------------------------------------
// Link GRU: one thread per link. x = m_link[l], h = link_state[l].
// ---------------------------------------------------------------------------
__global__ __launch_bounds__(256) void link_step(
    const float* __restrict__ m_link,
    const float* __restrict__ lk,
    const float* __restrict__ lrec,
    const float* __restrict__ lbias,
    float* __restrict__ link_state)
{
  __shared__ float Kt[96*32];
  __shared__ float Rt[96*32];
  __shared__ float B0[96], B1[96];
  for (int k = threadIdx.x; k < 96*32; k += 256){
    const int i = k & 31, j = k >> 5;
    Kt[k] = lk[i*96 + j];
    Rt[k] = lrec[i*96 + j];
  }
  if (threadIdx.x < 96){
    B0[threadIdx.x] = lbias[threadIdx.x];
    B1[threadIdx.x] = lbias[96 + threadIdx.x];
  }
  __syncthreads();

  const int l = blockIdx.x*256 + threadIdx.x;
  if (l >= N_LINKS_C) return;

  float x[32], h[32];
  {
    const float4* xv = reinterpret_cast<const float4*>(m_link + (size_t)l*D_C);
    const float4* hv = reinterpret_cast<const float4*>(link_state + (size_t)l*D_C);
    #pragma unroll
    for (int q=0;q<8;q++){
      float4 a = xv[q]; x[q*4]=a.x; x[q*4+1]=a.y; x[q*4+2]=a.z; x[q*4+3]=a.w;
      float4 b = hv[q]; h[q*4]=b.x; h[q*4+1]=b.y; h[q*4+2]=b.z; h[q*4+3]=b.w;
    }
  }
  float hn[32];
  #pragma unroll
  for (int d=0; d<32; d++){
    float xz=B0[d], xrg=B0[32+d], xh=B0[64+d];
    float hz=B1[d], hr=B1[32+d], hh=B1[64+d];
    const float4* kz = reinterpret_cast<const float4*>(Kt + d*32);
    const float4* kr = reinterpret_cast<const float4*>(Kt + (32+d)*32);
    const float4* kh = reinterpret_cast<const float4*>(Kt + (64+d)*32);
    const float4* rz = reinterpret_cast<const float4*>(Rt + d*32);
    const float4* rr = reinterpret_cast<const float4*>(Rt + (32+d)*32);
    const float4* rh = reinterpret_cast<const float4*>(Rt + (64+d)*32);
    #pragma unroll
    for (int i4=0;i4<8;i4++){
      const float4 a1 = kz[i4], a2 = kr[i4], a3 = kh[i4];
      const float4 b1 = rz[i4], b2 = rr[i4], b3 = rh[i4];
      xz  = fmaf(a1.x,x[i4*4+0],fmaf(a1.y,x[i4*4+1],fmaf(a1.z,x[i4*4+2],fmaf(a1.w,x[i4*4+3],xz))));
      xrg = fmaf(a2.x,x[i4*4+0],fmaf(a2.y,x[i4*4+1],fmaf(a2.z,x[i4*4+2],fmaf(a2.w,x[i4*4+3],xrg))));
      xh  = fmaf(a3.x,x[i4*4+0],fmaf(a3.y,x[i4*4+1],fmaf(a3.z,x[i4*4+2],fmaf(a3.w,x[i4*4+3],xh))));
      hz  = fmaf(b1.x,h[i4*4+0],fmaf(b1.y,h[i4*4+1],fmaf(b1.z,h[i4*4+2],fmaf(b1.w,h[i4*4+3],hz))));
      hr  = fmaf(b2.x,h[i4*4+0],fmaf(b2.y,h[i4*4+1],fmaf(b2.z,h[i4*4+2],fmaf(b2.w,h[i4*4+3],hr))));
      hh  = fmaf(b3.x,h[i4*4+0],fmaf(b3.y,h[i4*4+1],fmaf(b3.z,h[i4*4+2],fmaf(b3.w,h[i4*4+3],hh))));
    }
    const float z = sigm(xz + hz);
    const float r = sigm(xrg + hr);
    const float c2 = tanh_fast(xh + r*hh);
    hn[d] = z*h[d] + (1.0f - z)*c2;
  }
  float4* ov = reinterpret_cast<float4*>(link_state + (size_t)l*D_C);
  #pragma unroll
  for (int q=0;q<8;q++){
    float4 v; v.x=hn[q*4]; v.y=hn[q*4+1]; v.z=hn[q*4+2]; v.w=hn[q*4+3];
    ov[q]=v;
  }
}

// ---------------------------------------------------------------------------
// Readout MLP: 16 paths per 256-thread block; h1 staged in LDS.
// ---------------------------------------------------------------------------
#define PB 16
__global__ __launch_bounds__(256) void readout(
    const float* __restrict__ path_state,
    const float* __restrict__ w1, const float* __restrict__ b1,
    const float* __restrict__ w2, const float* __restrict__ b2,
    const float* __restrict__ w3, const float* __restrict__ b3,
    float* __restrict__ out)
{
  __shared__ float h1s[PB][RU_C];   // 16 KB
  __shared__ float hin[PB][D_C];    // 2 KB
  __shared__ float red[PB][4];
  const int k = threadIdx.x;
  const int pbase = blockIdx.x*PB;

  for (int idx = k; idx < PB*D_C; idx += 256)
    hin[idx>>5][idx&31] = path_state[(size_t)pbase*D_C + idx];
  __syncthreads();

  #pragma unroll 1
  for (int pp=0; pp<PB; pp++){
    float acc = b1[k];
    #pragma unroll
    for (int i=0;i<D_C;i++) acc = fmaf(hin[pp][i], w1[i*RU_C+k], acc);
    // selu
    acc = (acc > 0.f) ? 1.0507009873554805f*acc
                      : 1.7580993408473766f*(__expf(acc)-1.0f);
    h1s[pp][k] = acc;
  }
  __syncthreads();

  float acc2[PB];
  #pragma unroll
  for (int pp=0;pp<PB;pp++) acc2[pp] = b2[k];

  #pragma unroll 1
  for (int j=0;j<RU_C;j+=4){
    const float wa = w2[(j+0)*RU_C+k];
    const float wb = w2[(j+1)*RU_C+k];
    const float wc = w2[(j+2)*RU_C+k];
    const float wd = w2[(j+3)*RU_C+k];
    #pragma unroll
    for (int pp=0;pp<PB;pp++){
      const float4 hv = *reinterpret_cast<const float4*>(&h1s[pp][j]);
      acc2[pp] = fmaf(hv.x,wa,fmaf(hv.y,wb,fmaf(hv.z,wc,fmaf(hv.w,wd,acc2[pp]))));
    }
  }

  const float w3k = w3[k];
  const int lane = k & 63, wid = k >> 6;
  #pragma unroll
  for (int pp=0;pp<PB;pp++){
    float v = fmaxf(acc2[pp], 0.f) * w3k;
    #pragma unroll
    for (int off=32; off; off>>=1) v += __shfl_down(v, off, 64);
    if (lane == 0) red[pp][wid] = v;
  }
  __syncthreads();
  if (k < PB)
    out[pbase + k] = red[k][0]+red[k][1]+red[k][2]+red[k][3] + b3[0];
}

// ---------------------------------------------------------------------------
extern "C" void kernel_launch(void* const* d_in, const int* in_sizes, int n_in,
                              void* d_out, int out_size, void* d_ws, size_t ws_size,
                              hipStream_t stream)
{
  const float* cap   = (const float*)d_in[0];
  const float* bw    = (const float*)d_in[1];
  const int*   links = (const int*)  d_in[2];
  const float* pk    = (const float*)d_in[5];
  const float* prec  = (const float*)d_in[6];
  const float* pbias = (const float*)d_in[7];
  const float* lk    = (const float*)d_in[8];
  const float* lrec  = (const float*)d_in[9];
  const float* lbias = (const float*)d_in[10];
  const float* w1    = (const float*)d_in[11];
  const float* b1    = (const float*)d_in[12];
  const float* w2    = (const float*)d_in[13];
  const float* b2    = (const float*)d_in[14];
  const float* w3    = (const float*)d_in[15];
  const float* b3    = (const float*)d_in[16];
  float* out = (float*)d_out;

  char* ws = (char*)d_ws;
  float* path_state = (float*)(ws);                          // 16,777,216 B
  float* link_state = (float*)(ws + 16777216);               //  1,280,000 B
  float* m_link     = (float*)(ws + 18057216);               //  1,280,000 B
  float* xw         = (float*)(ws + 19337216);               //  3,840,000 B

  init_states<<<N_PATHS_C/256, 256, 0, stream>>>(cap, bw, link_state, path_state);

  for (int t=0; t<T_C; t++){
    precompute_xw<<<(N_LINKS_C*96)/256, 256, 0, stream>>>(link_state, pk, pbias, xw);
    hipMemsetAsync(m_link, 0, (size_t)N_LINKS_C*D_C*sizeof(float), stream);
    path_step<<<N_PATHS_C/256, 256, 0, stream>>>(xw, links, prec, pbias, path_state, m_link);
    link_step<<<(N_LINKS_C+255)/256, 256, 0, stream>>>(m_link, lk, lrec, lbias, link_state);
  }

  readout<<<N_PATHS_C/PB, 256, 0, stream>>>(path_state, w1, b1, w2, b2, w3, b3, out);
}

// Round 2
// 4939.534 us; speedup vs baseline: 3.1251x; 3.1251x over previous
//
#include <hip/hip_runtime.h>

#define N_LINKS_C 10000
#define N_PATHS_C 131072
#define N_EDGES_C (N_PATHS_C*8)
#define D_C 32
#define L_C 8
#define T_C 8
#define RU_C 256

__device__ __forceinline__ float sigm(float x){
  return __builtin_amdgcn_rcpf(1.0f + __expf(-x));
}
__device__ __forceinline__ float tanh_fast(float x){
  float e = __expf(2.0f*x);
  return 1.0f - 2.0f*__builtin_amdgcn_rcpf(e + 1.0f);
}

// ---------------------------------------------------------------------------
__global__ __launch_bounds__(256) void init_states(
    const float* __restrict__ cap, const float* __restrict__ bw,
    float* __restrict__ link_state, float* __restrict__ path_state)
{
  const int i = blockIdx.x*256 + threadIdx.x;
  if (i < N_PATHS_C){
    float4* r = reinterpret_cast<float4*>(path_state + (size_t)i*D_C);
    float4 z = make_float4(0.f,0.f,0.f,0.f);
    float4 f = make_float4(bw[i],0.f,0.f,0.f);
    r[0]=f;
    #pragma unroll
    for (int q=1;q<8;q++) r[q]=z;
  }
  if (i < N_LINKS_C){
    float4* r = reinterpret_cast<float4*>(link_state + (size_t)i*D_C);
    float4 z = make_float4(0.f,0.f,0.f,0.f);
    float4 f = make_float4(cap[i],0.f,0.f,0.f);
    r[0]=f;
    #pragma unroll
    for (int q=1;q<8;q++) r[q]=z;
  }
}

// ---------------------------------------------------------------------------
// CSR build: histogram -> exclusive scan -> per-edge destination slot
// ---------------------------------------------------------------------------
__global__ __launch_bounds__(256) void build_hist(
    const int* __restrict__ links, int* __restrict__ counts)
{
  const int e = blockIdx.x*256 + threadIdx.x;
  if (e < N_EDGES_C) atomicAdd(&counts[links[e]], 1);
}

__global__ __launch_bounds__(256) void scan_offsets(
    const int* __restrict__ counts, int* __restrict__ offsets)
{
  __shared__ int sums[256];
  const int t = threadIdx.x;
  const int base = t*40;                 // 256*40 = 10240 >= 10000
  int vals[40];
  int local = 0;
  #pragma unroll
  for (int k=0;k<40;k++){
    const int idx = base+k;
    const int c = (idx < N_LINKS_C) ? counts[idx] : 0;
    vals[k] = local; local += c;
  }
  sums[t] = local;
  __syncthreads();
  for (int d2=1; d2<256; d2<<=1){
    int v = (t>=d2) ? sums[t-d2] : 0;
    __syncthreads();
    sums[t] += v;
    __syncthreads();
  }
  const int off = sums[t] - local;       // exclusive prefix of this chunk
  #pragma unroll
  for (int k=0;k<40;k++){
    const int idx = base+k;
    if (idx < N_LINKS_C) offsets[idx] = off + vals[k];
  }
  if (t == 255) offsets[N_LINKS_C] = sums[255];
}

__global__ __launch_bounds__(256) void build_dest(
    const int* __restrict__ links, const int* __restrict__ offsets,
    int* __restrict__ cursor, int* __restrict__ dest)
{
  const int e = blockIdx.x*256 + threadIdx.x;
  if (e >= N_EDGES_C) return;
  const int l = links[e];
  dest[e] = offsets[l] + atomicAdd(&cursor[l], 1);
}

// ---------------------------------------------------------------------------
// xw[l][j] = link_state[l] . path_kernel[:,j] + path_bias[0][j]
// ---------------------------------------------------------------------------
__global__ __launch_bounds__(256) void precompute_xw(
    const float* __restrict__ link_state,
    const float* __restrict__ pk,
    const float* __restrict__ pbias,
    float* __restrict__ xw)
{
  const int tid = blockIdx.x*256 + threadIdx.x;
  if (tid >= N_LINKS_C*96) return;
  const int l = tid/96, j = tid - l*96;
  const float4* x4 = reinterpret_cast<const float4*>(link_state + (size_t)l*D_C);
  float acc = pbias[j];
  #pragma unroll
  for (int i4=0;i4<8;i4++){
    const float4 xv = x4[i4];
    acc = fmaf(xv.x, pk[(i4*4+0)*96+j],
          fmaf(xv.y, pk[(i4*4+1)*96+j],
          fmaf(xv.z, pk[(i4*4+2)*96+j],
          fmaf(xv.w, pk[(i4*4+3)*96+j], acc))));
  }
  xw[tid] = acc;
}

// ---------------------------------------------------------------------------
// Path GRU scan over L=8 links. USE_CSR=1: write h snapshot to CSR slot
// (scattered 128B rows, no atomics). USE_CSR=0: legacy atomic segment-sum.
// ---------------------------------------------------------------------------
template<int USE_CSR>
__global__ __launch_bounds__(256, 4) void path_step(
    const float* __restrict__ xw,       // [N_LINKS][96], bias0 folded in
    const int*   __restrict__ links,    // [E]
    const int*   __restrict__ dest,     // [E] CSR slot per edge (USE_CSR)
    const float* __restrict__ prec,     // path_rec [32][96]
    const float* __restrict__ pbias,    // [2][96]
    float* __restrict__ path_state,     // [N_PATHS][32]
    float* __restrict__ m_out)          // m_edge [E][32] or m_link (atomic)
{
  __shared__ float Rt[96*32];           // Rt[j][i] = prec[i][j]
  __shared__ float B1[96];
  for (int k = threadIdx.x; k < 96*32; k += 256)
    Rt[k] = prec[(k & 31)*96 + (k >> 5)];
  if (threadIdx.x < 96) B1[threadIdx.x] = pbias[96 + threadIdx.x];
  __syncthreads();

  const int p = blockIdx.x*256 + threadIdx.x;
  float h[32];
  {
    const float4* ps4 = reinterpret_cast<const float4*>(path_state + (size_t)p*D_C);
    #pragma unroll
    for (int q=0;q<8;q++){ float4 v = ps4[q]; h[q*4]=v.x; h[q*4+1]=v.y; h[q*4+2]=v.z; h[q*4+3]=v.w; }
  }

  #pragma unroll 1
  for (int s=0;s<L_C;s++){
    const int l = links[p*8+s];
    const float* xr = xw + (size_t)l*96;
    float hn[32];
    #pragma unroll
    for (int d0=0; d0<32; d0+=4){
      const float4 xz4 = *reinterpret_cast<const float4*>(xr + d0);
      const float4 xr4 = *reinterpret_cast<const float4*>(xr + 32 + d0);
      const float4 xh4 = *reinterpret_cast<const float4*>(xr + 64 + d0);
      #pragma unroll
      for (int q=0;q<4;q++){
        const int d = d0+q;
        float hz = B1[d], hr = B1[32+d], hh = B1[64+d];
        const float4* rz = reinterpret_cast<const float4*>(Rt + d*32);
        const float4* rr = reinterpret_cast<const float4*>(Rt + (32+d)*32);
        const float4* rh = reinterpret_cast<const float4*>(Rt + (64+d)*32);
        #pragma unroll
        for (int i4=0;i4<8;i4++){
          const float4 a = rz[i4], b = rr[i4], c = rh[i4];
          hz = fmaf(a.x,h[i4*4+0],fmaf(a.y,h[i4*4+1],fmaf(a.z,h[i4*4+2],fmaf(a.w,h[i4*4+3],hz))));
          hr = fmaf(b.x,h[i4*4+0],fmaf(b.y,h[i4*4+1],fmaf(b.z,h[i4*4+2],fmaf(b.w,h[i4*4+3],hr))));
          hh = fmaf(c.x,h[i4*4+0],fmaf(c.y,h[i4*4+1],fmaf(c.z,h[i4*4+2],fmaf(c.w,h[i4*4+3],hh))));
        }
        const float xzv = (q==0)?xz4.x:(q==1)?xz4.y:(q==2)?xz4.z:xz4.w;
        const float xrv = (q==0)?xr4.x:(q==1)?xr4.y:(q==2)?xr4.z:xr4.w;
        const float xhv = (q==0)?xh4.x:(q==1)?xh4.y:(q==2)?xh4.z:xh4.w;
        const float z = sigm(xzv + hz);
        const float r = sigm(xrv + hr);
        const float c2 = tanh_fast(xhv + r*hh);
        hn[d] = z*h[d] + (1.0f - z)*c2;
      }
    }
    if (USE_CSR){
      float* mr = m_out + (size_t)dest[p*8+s]*D_C;
      float4* mv = reinterpret_cast<float4*>(mr);
      #pragma unroll
      for (int q=0;q<8;q++){
        float4 v; v.x=hn[q*4]; v.y=hn[q*4+1]; v.z=hn[q*4+2]; v.w=hn[q*4+3];
        mv[q]=v;
      }
      #pragma unroll
      for (int d=0; d<32; d++) h[d]=hn[d];
    } else {
      float* ml = m_out + (size_t)l*D_C;
      #pragma unroll
      for (int d=0; d<32; d++){ h[d]=hn[d]; atomicAdd(ml+d, h[d]); }
    }
  }

  float4* ps4w = reinterpret_cast<float4*>(path_state + (size_t)p*D_C);
  #pragma unroll
  for (int q=0;q<8;q++){
    float4 v; v.x=h[q*4]; v.y=h[q*4+1]; v.z=h[q*4+2]; v.w=h[q*4+3];
    ps4w[q]=v;
  }
}

// ---------------------------------------------------------------------------
// Segmented sum: one wave per link, contiguous CSR range, coalesced reads.
// ---------------------------------------------------------------------------
__global__ __launch_bounds__(256) void gather_m(
    const float* __restrict__ m_edge,
    const int* __restrict__ offsets,
    float* __restrict__ m_link)
{
  const int wid = threadIdx.x >> 6, lane = threadIdx.x & 63;
  const int l = blockIdx.x*4 + wid;
  if (l >= N_LINKS_C) return;
  const int s0 = offsets[l], s1 = offsets[l+1];
  const int d = lane & 31, half = lane >> 5;
  float acc = 0.f;
  for (int i = s0 + half; i < s1; i += 2)
    acc += m_edge[(size_t)i*D_C + d];
  acc += __shfl_down(acc, 32, 64);
  if (lane < 32) m_link[(size_t)l*D_C + d] = acc;
}

// ---------------------------------------------------------------------------
// Link GRU: one thread per link.
// ---------------------------------------------------------------------------
__global__ __launch_bounds__(256) void link_step(
    const float* __restrict__ m_link,
    const float* __restrict__ lk,
    const float* __restrict__ lrec,
    const float* __restrict__ lbias,
    float* __restrict__ link_state)
{
  __shared__ float Kt[96*32];
  __shared__ float Rt[96*32];
  __shared__ float B0[96], B1[96];
  for (int k = threadIdx.x; k < 96*32; k += 256){
    const int i = k & 31, j = k >> 5;
    Kt[k] = lk[i*96 + j];
    Rt[k] = lrec[i*96 + j];
  }
  if (threadIdx.x < 96){
    B0[threadIdx.x] = lbias[threadIdx.x];
    B1[threadIdx.x] = lbias[96 + threadIdx.x];
  }
  __syncthreads();

  const int l = blockIdx.x*256 + threadIdx.x;
  if (l >= N_LINKS_C) return;

  float x[32], h[32];
  {
    const float4* xv = reinterpret_cast<const float4*>(m_link + (size_t)l*D_C);
    const float4* hv = reinterpret_cast<const float4*>(link_state + (size_t)l*D_C);
    #pragma unroll
    for (int q=0;q<8;q++){
      float4 a = xv[q]; x[q*4]=a.x; x[q*4+1]=a.y; x[q*4+2]=a.z; x[q*4+3]=a.w;
      float4 b = hv[q]; h[q*4]=b.x; h[q*4+1]=b.y; h[q*4+2]=b.z; h[q*4+3]=b.w;
    }
  }
  float hn[32];
  #pragma unroll
  for (int d=0; d<32; d++){
    float xz=B0[d], xrg=B0[32+d], xh=B0[64+d];
    float hz=B1[d], hr=B1[32+d], hh=B1[64+d];
    const float4* kz = reinterpret_cast<const float4*>(Kt + d*32);
    const float4* kr = reinterpret_cast<const float4*>(Kt + (32+d)*32);
    const float4* kh = reinterpret_cast<const float4*>(Kt + (64+d)*32);
    const float4* rz = reinterpret_cast<const float4*>(Rt + d*32);
    const float4* rr = reinterpret_cast<const float4*>(Rt + (32+d)*32);
    const float4* rh = reinterpret_cast<const float4*>(Rt + (64+d)*32);
    #pragma unroll
    for (int i4=0;i4<8;i4++){
      const float4 a1 = kz[i4], a2 = kr[i4], a3 = kh[i4];
      const float4 b1 = rz[i4], b2 = rr[i4], b3 = rh[i4];
      xz  = fmaf(a1.x,x[i4*4+0],fmaf(a1.y,x[i4*4+1],fmaf(a1.z,x[i4*4+2],fmaf(a1.w,x[i4*4+3],xz))));
      xrg = fmaf(a2.x,x[i4*4+0],fmaf(a2.y,x[i4*4+1],fmaf(a2.z,x[i4*4+2],fmaf(a2.w,x[i4*4+3],xrg))));
      xh  = fmaf(a3.x,x[i4*4+0],fmaf(a3.y,x[i4*4+1],fmaf(a3.z,x[i4*4+2],fmaf(a3.w,x[i4*4+3],xh))));
      hz  = fmaf(b1.x,h[i4*4+0],fmaf(b1.y,h[i4*4+1],fmaf(b1.z,h[i4*4+2],fmaf(b1.w,h[i4*4+3],hz))));
      hr  = fmaf(b2.x,h[i4*4+0],fmaf(b2.y,h[i4*4+1],fmaf(b2.z,h[i4*4+2],fmaf(b2.w,h[i4*4+3],hr))));
      hh  = fmaf(b3.x,h[i4*4+0],fmaf(b3.y,h[i4*4+1],fmaf(b3.z,h[i4*4+2],fmaf(b3.w,h[i4*4+3],hh))));
    }
    const float z = sigm(xz + hz);
    const float r = sigm(xrg + hr);
    const float c2 = tanh_fast(xh + r*hh);
    hn[d] = z*h[d] + (1.0f - z)*c2;
  }
  float4* ov = reinterpret_cast<float4*>(link_state + (size_t)l*D_C);
  #pragma unroll
  for (int q=0;q<8;q++){
    float4 v; v.x=hn[q*4]; v.y=hn[q*4+1]; v.z=hn[q*4+2]; v.w=hn[q*4+3];
    ov[q]=v;
  }
}

// ---------------------------------------------------------------------------
// Readout MLP: 16 paths per 256-thread block; h1 staged in LDS.
// ---------------------------------------------------------------------------
#define PB 16
__global__ __launch_bounds__(256) void readout(
    const float* __restrict__ path_state,
    const float* __restrict__ w1, const float* __restrict__ b1,
    const float* __restrict__ w2, const float* __restrict__ b2,
    const float* __restrict__ w3, const float* __restrict__ b3,
    float* __restrict__ out)
{
  __shared__ float h1s[PB][RU_C];   // 16 KB
  __shared__ float hin[PB][D_C];    // 2 KB
  __shared__ float red[PB][4];
  const int k = threadIdx.x;
  const int pbase = blockIdx.x*PB;

  for (int idx = k; idx < PB*D_C; idx += 256)
    hin[idx>>5][idx&31] = path_state[(size_t)pbase*D_C + idx];
  __syncthreads();

  #pragma unroll 1
  for (int pp=0; pp<PB; pp++){
    float acc = b1[k];
    #pragma unroll
    for (int i=0;i<D_C;i++) acc = fmaf(hin[pp][i], w1[i*RU_C+k], acc);
    acc = (acc > 0.f) ? 1.0507009873554805f*acc
                      : 1.7580993408473766f*(__expf(acc)-1.0f);
    h1s[pp][k] = acc;
  }
  __syncthreads();

  float acc2[PB];
  #pragma unroll
  for (int pp=0;pp<PB;pp++) acc2[pp] = b2[k];

  #pragma unroll 1
  for (int j=0;j<RU_C;j+=4){
    const float wa = w2[(j+0)*RU_C+k];
    const float wb = w2[(j+1)*RU_C+k];
    const float wc = w2[(j+2)*RU_C+k];
    const float wd = w2[(j+3)*RU_C+k];
    #pragma unroll
    for (int pp=0;pp<PB;pp++){
      const float4 hv = *reinterpret_cast<const float4*>(&h1s[pp][j]);
      acc2[pp] = fmaf(hv.x,wa,fmaf(hv.y,wb,fmaf(hv.z,wc,fmaf(hv.w,wd,acc2[pp]))));
    }
  }

  const float w3k = w3[k];
  const int lane = k & 63, wid = k >> 6;
  #pragma unroll
  for (int pp=0;pp<PB;pp++){
    float v = fmaxf(acc2[pp], 0.f) * w3k;
    #pragma unroll
    for (int off=32; off; off>>=1) v += __shfl_down(v, off, 64);
    if (lane == 0) red[pp][wid] = v;
  }
  __syncthreads();
  if (k < PB)
    out[pbase + k] = red[k][0]+red[k][1]+red[k][2]+red[k][3] + b3[0];
}

// ---------------------------------------------------------------------------
extern "C" void kernel_launch(void* const* d_in, const int* in_sizes, int n_in,
                              void* d_out, int out_size, void* d_ws, size_t ws_size,
                              hipStream_t stream)
{
  const float* cap   = (const float*)d_in[0];
  const float* bw    = (const float*)d_in[1];
  const int*   links = (const int*)  d_in[2];
  const float* pk    = (const float*)d_in[5];
  const float* prec  = (const float*)d_in[6];
  const float* pbias = (const float*)d_in[7];
  const float* lk    = (const float*)d_in[8];
  const float* lrec  = (const float*)d_in[9];
  const float* lbias = (const float*)d_in[10];
  const float* w1    = (const float*)d_in[11];
  const float* b1    = (const float*)d_in[12];
  const float* w2    = (const float*)d_in[13];
  const float* b2    = (const float*)d_in[14];
  const float* w3    = (const float*)d_in[15];
  const float* b3    = (const float*)d_in[16];
  float* out = (float*)d_out;

  char* ws = (char*)d_ws;
  float* path_state = (float*)(ws);                      // 16,777,216
  float* link_state = (float*)(ws + 16777216);           //  1,280,000
  float* m_link     = (float*)(ws + 18057216);           //  1,280,000
  float* xw         = (float*)(ws + 19337216);           //  3,840,000
  int*   counts     = (int*)  (ws + 23177216);           //     40,000
  int*   cursor     = (int*)  (ws + 23217216);           //     40,000
  int*   offsets    = (int*)  (ws + 23257216);           //     40,064
  int*   dest       = (int*)  (ws + 23297280);           //  4,194,304
  float* m_edge     = (float*)(ws + 27491584);           // 134,217,728  (end 161,709,312)

  const bool use_csr = (ws_size >= 161709312ull);

  init_states<<<N_PATHS_C/256, 256, 0, stream>>>(cap, bw, link_state, path_state);

  if (use_csr){
    hipMemsetAsync(counts, 0, 80000, stream);   // counts + cursor (contiguous)
    build_hist  <<<N_EDGES_C/256, 256, 0, stream>>>(links, counts);
    scan_offsets<<<1, 256, 0, stream>>>(counts, offsets);
    build_dest  <<<N_EDGES_C/256, 256, 0, stream>>>(links, offsets, cursor, dest);

    for (int t=0; t<T_C; t++){
      precompute_xw<<<(N_LINKS_C*96)/256, 256, 0, stream>>>(link_state, pk, pbias, xw);
      path_step<1><<<N_PATHS_C/256, 256, 0, stream>>>(xw, links, dest, prec, pbias, path_state, m_edge);
      gather_m<<<(N_LINKS_C+3)/4, 256, 0, stream>>>(m_edge, offsets, m_link);
      link_step<<<(N_LINKS_C+255)/256, 256, 0, stream>>>(m_link, lk, lrec, lbias, link_state);
    }
  } else {
    for (int t=0; t<T_C; t++){
      precompute_xw<<<(N_LINKS_C*96)/256, 256, 0, stream>>>(link_state, pk, pbias, xw);
      hipMemsetAsync(m_link, 0, (size_t)N_LINKS_C*D_C*sizeof(float), stream);
      path_step<0><<<N_PATHS_C/256, 256, 0, stream>>>(xw, links, dest, prec, pbias, path_state, m_link);
      link_step<<<(N_LINKS_C+255)/256, 256, 0, stream>>>(m_link, lk, lrec, lbias, link_state);
    }
  }

  readout<<<N_PATHS_C/PB, 256, 0, stream>>>(path_state, w1, b1, w2, b2, w3, b3, out);
}

// Round 3
// 2129.826 us; speedup vs baseline: 7.2479x; 2.3192x over previous
//
#include <hip/hip_runtime.h>

#define N_LINKS_C 10000
#define N_PATHS_C 131072
#define N_EDGES_C (N_PATHS_C*8)
#define D_C 32
#define L_C 8
#define T_C 8
#define RU_C 256

__device__ __forceinline__ float sigm(float x){
  return __builtin_amdgcn_rcpf(1.0f + __expf(-x));
}
__device__ __forceinline__ float tanh_fast(float x){
  float e = __expf(2.0f*x);
  return 1.0f - 2.0f*__builtin_amdgcn_rcpf(e + 1.0f);
}

// ---------------------------------------------------------------------------
__global__ __launch_bounds__(256) void init_states(
    const float* __restrict__ cap, const float* __restrict__ bw,
    float* __restrict__ link_state, float* __restrict__ path_state)
{
  const int i = blockIdx.x*256 + threadIdx.x;
  if (i < N_PATHS_C){
    float4* r = reinterpret_cast<float4*>(path_state + (size_t)i*D_C);
    float4 z = make_float4(0.f,0.f,0.f,0.f);
    float4 f = make_float4(bw[i],0.f,0.f,0.f);
    r[0]=f;
    #pragma unroll
    for (int q=1;q<8;q++) r[q]=z;
  }
  if (i < N_LINKS_C){
    float4* r = reinterpret_cast<float4*>(link_state + (size_t)i*D_C);
    float4 z = make_float4(0.f,0.f,0.f,0.f);
    float4 f = make_float4(cap[i],0.f,0.f,0.f);
    r[0]=f;
    #pragma unroll
    for (int q=1;q<8;q++) r[q]=z;
  }
}

// ---------------------------------------------------------------------------
// CSR build: histogram -> exclusive scan -> per-edge destination slot
// ---------------------------------------------------------------------------
__global__ __launch_bounds__(256) void build_hist(
    const int* __restrict__ links, int* __restrict__ counts)
{
  const int e = blockIdx.x*256 + threadIdx.x;
  if (e < N_EDGES_C) atomicAdd(&counts[links[e]], 1);
}

__global__ __launch_bounds__(256) void scan_offsets(
    const int* __restrict__ counts, int* __restrict__ offsets)
{
  __shared__ int sums[256];
  const int t = threadIdx.x;
  const int base = t*40;                 // 256*40 = 10240 >= 10000
  int vals[40];
  int local = 0;
  #pragma unroll
  for (int k=0;k<40;k++){
    const int idx = base+k;
    const int c = (idx < N_LINKS_C) ? counts[idx] : 0;
    vals[k] = local; local += c;
  }
  sums[t] = local;
  __syncthreads();
  for (int d2=1; d2<256; d2<<=1){
    int v = (t>=d2) ? sums[t-d2] : 0;
    __syncthreads();
    sums[t] += v;
    __syncthreads();
  }
  const int off = sums[t] - local;       // exclusive prefix of this chunk
  #pragma unroll
  for (int k=0;k<40;k++){
    const int idx = base+k;
    if (idx < N_LINKS_C) offsets[idx] = off + vals[k];
  }
  if (t == 255) offsets[N_LINKS_C] = sums[255];
}

__global__ __launch_bounds__(256) void build_dest(
    const int* __restrict__ links, const int* __restrict__ offsets,
    int* __restrict__ cursor, int* __restrict__ dest)
{
  const int e = blockIdx.x*256 + threadIdx.x;
  if (e >= N_EDGES_C) return;
  const int l = links[e];
  dest[e] = offsets[l] + atomicAdd(&cursor[l], 1);
}

// ---------------------------------------------------------------------------
// xw[l][j] = link_state[l] . path_kernel[:,j] + path_bias[0][j]  (t=0 only)
// ---------------------------------------------------------------------------
__global__ __launch_bounds__(256) void precompute_xw(
    const float* __restrict__ link_state,
    const float* __restrict__ pk,
    const float* __restrict__ pbias,
    float* __restrict__ xw)
{
  const int tid = blockIdx.x*256 + threadIdx.x;
  if (tid >= N_LINKS_C*96) return;
  const int l = tid/96, j = tid - l*96;
  const float4* x4 = reinterpret_cast<const float4*>(link_state + (size_t)l*D_C);
  float acc = pbias[j];
  #pragma unroll
  for (int i4=0;i4<8;i4++){
    const float4 xv = x4[i4];
    acc = fmaf(xv.x, pk[(i4*4+0)*96+j],
          fmaf(xv.y, pk[(i4*4+1)*96+j],
          fmaf(xv.z, pk[(i4*4+2)*96+j],
          fmaf(xv.w, pk[(i4*4+3)*96+j], acc))));
  }
  xw[tid] = acc;
}

// ---------------------------------------------------------------------------
// Path GRU, half-wave per path: lane d owns output dim d. Recurrent weights
// in 96 VGPRs/lane; h exchanged via LDS broadcast; coalesced xw gather;
// nontemporal m_edge/path_state writes (keep xw L2-resident).
// ---------------------------------------------------------------------------
__global__ __launch_bounds__(256, 3) void path_step3(
    const float* __restrict__ xw,       // [N_LINKS][96], bias0 folded in
    const int*   __restrict__ links,    // [E]
    const int*   __restrict__ dest,     // [E]
    const float* __restrict__ prec,     // [32][96]
    const float* __restrict__ pbias,    // [2][96]
    float* __restrict__ path_state,     // [N_PATHS][32]
    float* __restrict__ m_edge)         // [E][32]
{
  __shared__ float hbuf[8][32];         // one row per path slot
  const int tid = threadIdx.x;
  const int wave = tid >> 6, lane = tid & 63;
  const int half = lane >> 5, d = lane & 31;
  const int slot = wave*2 + half;
  const int p = blockIdx.x*8 + slot;

  float wz[32], wr[32], wh[32];
  #pragma unroll
  for (int i=0;i<32;i++){
    wz[i] = prec[i*96 + d];
    wr[i] = prec[i*96 + 32 + d];
    wh[i] = prec[i*96 + 64 + d];
  }
  const float bz = pbias[96 + d];
  const float br = pbias[96 + 32 + d];
  const float bh = pbias[96 + 64 + d];

  float h = __builtin_nontemporal_load(&path_state[(size_t)p*D_C + d]);
  hbuf[slot][d] = h;

  const int ebase = p*8;
  #pragma unroll 1
  for (int s=0;s<L_C;s++){
    const int l  = links[ebase+s];
    const int de = dest[ebase+s];
    const float* xr = xw + (size_t)l*96;
    const float xz_in = xr[d];
    const float xr_in = xr[32+d];
    const float xh_in = xr[64+d];

    float hz=bz, hr=br, hh=bh;
    const float4* hv4 = reinterpret_cast<const float4*>(hbuf[slot]);
    #pragma unroll
    for (int i4=0;i4<8;i4++){
      const float4 hq = hv4[i4];
      hz = fmaf(wz[i4*4+0],hq.x, fmaf(wz[i4*4+1],hq.y, fmaf(wz[i4*4+2],hq.z, fmaf(wz[i4*4+3],hq.w, hz))));
      hr = fmaf(wr[i4*4+0],hq.x, fmaf(wr[i4*4+1],hq.y, fmaf(wr[i4*4+2],hq.z, fmaf(wr[i4*4+3],hq.w, hr))));
      hh = fmaf(wh[i4*4+0],hq.x, fmaf(wh[i4*4+1],hq.y, fmaf(wh[i4*4+2],hq.z, fmaf(wh[i4*4+3],hq.w, hh))));
    }
    const float z = sigm(xz_in + hz);
    const float r = sigm(xr_in + hr);
    const float c = tanh_fast(xh_in + r*hh);
    h = z*h + (1.0f - z)*c;

    __builtin_nontemporal_store(h, &m_edge[(size_t)de*D_C + d]);
    hbuf[slot][d] = h;
  }
  __builtin_nontemporal_store(h, &path_state[(size_t)p*D_C + d]);
}

// ---------------------------------------------------------------------------
// Fused: segment-sum(m_edge) -> link GRU -> xw for next t-step.
// Half-wave per link; weights staged in LDS (conflict-free column reads).
// ---------------------------------------------------------------------------
__global__ __launch_bounds__(256) void link_fused(
    const float* __restrict__ m_edge,
    const int*   __restrict__ offsets,
    const float* __restrict__ lk,     // [32][96]
    const float* __restrict__ lrec,   // [32][96]
    const float* __restrict__ lbias,  // [2][96]
    const float* __restrict__ pk,     // [32][96]
    const float* __restrict__ pbias,  // [2][96]
    float* __restrict__ link_state,
    float* __restrict__ xw)
{
  __shared__ float Kt[3072];
  __shared__ float Rt[3072];
  __shared__ float Pk[3072];
  __shared__ float xb[8][32];
  __shared__ float hb[8][32];
  const int tid = threadIdx.x;
  for (int k = tid; k < 3072; k += 256){
    Kt[k] = lk[k]; Rt[k] = lrec[k]; Pk[k] = pk[k];
  }
  __syncthreads();

  const int wave = tid >> 6, lane = tid & 63;
  const int half = lane >> 5, d = lane & 31;
  const int slot = wave*2 + half;
  const int l = blockIdx.x*8 + slot;
  if (l >= N_LINKS_C) return;

  const int s0 = offsets[l], s1 = offsets[l+1];
  float a0=0.f, a1=0.f, a2=0.f, a3=0.f;
  int i = s0;
  for (; i+3 < s1; i += 4){
    a0 += __builtin_nontemporal_load(&m_edge[(size_t)(i  )*D_C + d]);
    a1 += __builtin_nontemporal_load(&m_edge[(size_t)(i+1)*D_C + d]);
    a2 += __builtin_nontemporal_load(&m_edge[(size_t)(i+2)*D_C + d]);
    a3 += __builtin_nontemporal_load(&m_edge[(size_t)(i+3)*D_C + d]);
  }
  for (; i < s1; ++i)
    a0 += __builtin_nontemporal_load(&m_edge[(size_t)i*D_C + d]);
  const float x_d = (a0+a1)+(a2+a3);

  const float h_d = link_state[(size_t)l*D_C + d];
  xb[slot][d] = x_d;
  hb[slot][d] = h_d;

  float xz=lbias[d], xrg=lbias[32+d], xh=lbias[64+d];
  float hz=lbias[96+d], hr=lbias[96+32+d], hh=lbias[96+64+d];
  #pragma unroll
  for (int i2=0;i2<32;i2++){
    const float xv = xb[slot][i2];
    const float hv = hb[slot][i2];
    xz  = fmaf(Kt[i2*96      + d], xv, xz);
    xrg = fmaf(Kt[i2*96 + 32 + d], xv, xrg);
    xh  = fmaf(Kt[i2*96 + 64 + d], xv, xh);
    hz  = fmaf(Rt[i2*96      + d], hv, hz);
    hr  = fmaf(Rt[i2*96 + 32 + d], hv, hr);
    hh  = fmaf(Rt[i2*96 + 64 + d], hv, hh);
  }
  const float z = sigm(xz + hz);
  const float r = sigm(xrg + hr);
  const float c = tanh_fast(xh + r*hh);
  const float hn = z*h_d + (1.0f - z)*c;
  link_state[(size_t)l*D_C + d] = hn;
  hb[slot][d] = hn;

  float o0=pbias[d], o1=pbias[32+d], o2=pbias[64+d];
  #pragma unroll
  for (int i2=0;i2<32;i2++){
    const float hv = hb[slot][i2];
    o0 = fmaf(Pk[i2*96      + d], hv, o0);
    o1 = fmaf(Pk[i2*96 + 32 + d], hv, o1);
    o2 = fmaf(Pk[i2*96 + 64 + d], hv, o2);
  }
  xw[(size_t)l*96      + d] = o0;
  xw[(size_t)l*96 + 32 + d] = o1;
  xw[(size_t)l*96 + 64 + d] = o2;
}

// ---------------------------------------------------------------------------
// Legacy kernels for the no-CSR fallback path
// ---------------------------------------------------------------------------
__global__ __launch_bounds__(256, 4) void path_step_atomic(
    const float* __restrict__ xw, const int* __restrict__ links,
    const float* __restrict__ prec, const float* __restrict__ pbias,
    float* __restrict__ path_state, float* __restrict__ m_out)
{
  __shared__ float Rt[96*32];
  __shared__ float B1[96];
  for (int k = threadIdx.x; k < 96*32; k += 256)
    Rt[k] = prec[(k & 31)*96 + (k >> 5)];
  if (threadIdx.x < 96) B1[threadIdx.x] = pbias[96 + threadIdx.x];
  __syncthreads();

  const int p = blockIdx.x*256 + threadIdx.x;
  float h[32];
  {
    const float4* ps4 = reinterpret_cast<const float4*>(path_state + (size_t)p*D_C);
    #pragma unroll
    for (int q=0;q<8;q++){ float4 v = ps4[q]; h[q*4]=v.x; h[q*4+1]=v.y; h[q*4+2]=v.z; h[q*4+3]=v.w; }
  }
  #pragma unroll 1
  for (int s=0;s<L_C;s++){
    const int l = links[p*8+s];
    const float* xr = xw + (size_t)l*96;
    float hn[32];
    #pragma unroll
    for (int d0=0; d0<32; d0+=4){
      #pragma unroll
      for (int q=0;q<4;q++){
        const int d = d0+q;
        float hz = B1[d], hr = B1[32+d], hh = B1[64+d];
        const float4* rz = reinterpret_cast<const float4*>(Rt + d*32);
        const float4* rr = reinterpret_cast<const float4*>(Rt + (32+d)*32);
        const float4* rh = reinterpret_cast<const float4*>(Rt + (64+d)*32);
        #pragma unroll
        for (int i4=0;i4<8;i4++){
          const float4 a = rz[i4], b = rr[i4], c = rh[i4];
          hz = fmaf(a.x,h[i4*4+0],fmaf(a.y,h[i4*4+1],fmaf(a.z,h[i4*4+2],fmaf(a.w,h[i4*4+3],hz))));
          hr = fmaf(b.x,h[i4*4+0],fmaf(b.y,h[i4*4+1],fmaf(b.z,h[i4*4+2],fmaf(b.w,h[i4*4+3],hr))));
          hh = fmaf(c.x,h[i4*4+0],fmaf(c.y,h[i4*4+1],fmaf(c.z,h[i4*4+2],fmaf(c.w,h[i4*4+3],hh))));
        }
        const float z = sigm(xr[d] + hz);
        const float r = sigm(xr[32+d] + hr);
        const float c2 = tanh_fast(xr[64+d] + r*hh);
        hn[d] = z*h[d] + (1.0f - z)*c2;
      }
    }
    float* ml = m_out + (size_t)l*D_C;
    #pragma unroll
    for (int d=0; d<32; d++){ h[d]=hn[d]; atomicAdd(ml+d, h[d]); }
  }
  float4* ps4w = reinterpret_cast<float4*>(path_state + (size_t)p*D_C);
  #pragma unroll
  for (int q=0;q<8;q++){
    float4 v; v.x=h[q*4]; v.y=h[q*4+1]; v.z=h[q*4+2]; v.w=h[q*4+3];
    ps4w[q]=v;
  }
}

__global__ __launch_bounds__(256) void link_step(
    const float* __restrict__ m_link,
    const float* __restrict__ lk, const float* __restrict__ lrec,
    const float* __restrict__ lbias, float* __restrict__ link_state)
{
  __shared__ float Kt[96*32];
  __shared__ float Rt[96*32];
  __shared__ float B0[96], B1[96];
  for (int k = threadIdx.x; k < 96*32; k += 256){
    const int i = k & 31, j = k >> 5;
    Kt[k] = lk[i*96 + j];
    Rt[k] = lrec[i*96 + j];
  }
  if (threadIdx.x < 96){
    B0[threadIdx.x] = lbias[threadIdx.x];
    B1[threadIdx.x] = lbias[96 + threadIdx.x];
  }
  __syncthreads();
  const int l = blockIdx.x*256 + threadIdx.x;
  if (l >= N_LINKS_C) return;
  float x[32], h[32];
  {
    const float4* xv = reinterpret_cast<const float4*>(m_link + (size_t)l*D_C);
    const float4* hv = reinterpret_cast<const float4*>(link_state + (size_t)l*D_C);
    #pragma unroll
    for (int q=0;q<8;q++){
      float4 a = xv[q]; x[q*4]=a.x; x[q*4+1]=a.y; x[q*4+2]=a.z; x[q*4+3]=a.w;
      float4 b = hv[q]; h[q*4]=b.x; h[q*4+1]=b.y; h[q*4+2]=b.z; h[q*4+3]=b.w;
    }
  }
  float hn[32];
  #pragma unroll
  for (int d=0; d<32; d++){
    float xz=B0[d], xrg=B0[32+d], xh=B0[64+d];
    float hz=B1[d], hr=B1[32+d], hh=B1[64+d];
    const float4* kz = reinterpret_cast<const float4*>(Kt + d*32);
    const float4* kr = reinterpret_cast<const float4*>(Kt + (32+d)*32);
    const float4* kh = reinterpret_cast<const float4*>(Kt + (64+d)*32);
    const float4* rz = reinterpret_cast<const float4*>(Rt + d*32);
    const float4* rr = reinterpret_cast<const float4*>(Rt + (32+d)*32);
    const float4* rh = reinterpret_cast<const float4*>(Rt + (64+d)*32);
    #pragma unroll
    for (int i4=0;i4<8;i4++){
      const float4 a1 = kz[i4], a2 = kr[i4], a3 = kh[i4];
      const float4 b1 = rz[i4], b2 = rr[i4], b3 = rh[i4];
      xz  = fmaf(a1.x,x[i4*4+0],fmaf(a1.y,x[i4*4+1],fmaf(a1.z,x[i4*4+2],fmaf(a1.w,x[i4*4+3],xz))));
      xrg = fmaf(a2.x,x[i4*4+0],fmaf(a2.y,x[i4*4+1],fmaf(a2.z,x[i4*4+2],fmaf(a2.w,x[i4*4+3],xrg))));
      xh  = fmaf(a3.x,x[i4*4+0],fmaf(a3.y,x[i4*4+1],fmaf(a3.z,x[i4*4+2],fmaf(a3.w,x[i4*4+3],xh))));
      hz  = fmaf(b1.x,h[i4*4+0],fmaf(b1.y,h[i4*4+1],fmaf(b1.z,h[i4*4+2],fmaf(b1.w,h[i4*4+3],hz))));
      hr  = fmaf(b2.x,h[i4*4+0],fmaf(b2.y,h[i4*4+1],fmaf(b2.z,h[i4*4+2],fmaf(b2.w,h[i4*4+3],hr))));
      hh  = fmaf(b3.x,h[i4*4+0],fmaf(b3.y,h[i4*4+1],fmaf(b3.z,h[i4*4+2],fmaf(b3.w,h[i4*4+3],hh))));
    }
    const float z = sigm(xz + hz);
    const float r = sigm(xrg + hr);
    const float c2 = tanh_fast(xh + r*hh);
    hn[d] = z*h[d] + (1.0f - z)*c2;
  }
  float4* ov = reinterpret_cast<float4*>(link_state + (size_t)l*D_C);
  #pragma unroll
  for (int q=0;q<8;q++){
    float4 v; v.x=hn[q*4]; v.y=hn[q*4+1]; v.z=hn[q*4+2]; v.w=hn[q*4+3];
    ov[q]=v;
  }
}

// ---------------------------------------------------------------------------
// Readout MLP: 16 paths per 256-thread block; h1 staged in LDS.
// ---------------------------------------------------------------------------
#define PB 16
__global__ __launch_bounds__(256) void readout(
    const float* __restrict__ path_state,
    const float* __restrict__ w1, const float* __restrict__ b1,
    const float* __restrict__ w2, const float* __restrict__ b2,
    const float* __restrict__ w3, const float* __restrict__ b3,
    float* __restrict__ out)
{
  __shared__ float h1s[PB][RU_C];   // 16 KB
  __shared__ float hin[PB][D_C];    // 2 KB
  __shared__ float red[PB][4];
  const int k = threadIdx.x;
  const int pbase = blockIdx.x*PB;

  for (int idx = k; idx < PB*D_C; idx += 256)
    hin[idx>>5][idx&31] = path_state[(size_t)pbase*D_C + idx];
  __syncthreads();

  #pragma unroll 1
  for (int pp=0; pp<PB; pp++){
    float acc = b1[k];
    #pragma unroll
    for (int i=0;i<D_C;i++) acc = fmaf(hin[pp][i], w1[i*RU_C+k], acc);
    acc = (acc > 0.f) ? 1.0507009873554805f*acc
                      : 1.7580993408473766f*(__expf(acc)-1.0f);
    h1s[pp][k] = acc;
  }
  __syncthreads();

  float acc2[PB];
  #pragma unroll
  for (int pp=0;pp<PB;pp++) acc2[pp] = b2[k];

  #pragma unroll 1
  for (int j=0;j<RU_C;j+=4){
    const float wa = w2[(j+0)*RU_C+k];
    const float wb = w2[(j+1)*RU_C+k];
    const float wc = w2[(j+2)*RU_C+k];
    const float wd = w2[(j+3)*RU_C+k];
    #pragma unroll
    for (int pp=0;pp<PB;pp++){
      const float4 hv = *reinterpret_cast<const float4*>(&h1s[pp][j]);
      acc2[pp] = fmaf(hv.x,wa,fmaf(hv.y,wb,fmaf(hv.z,wc,fmaf(hv.w,wd,acc2[pp]))));
    }
  }

  const float w3k = w3[k];
  const int lane = k & 63, wid = k >> 6;
  #pragma unroll
  for (int pp=0;pp<PB;pp++){
    float v = fmaxf(acc2[pp], 0.f) * w3k;
    #pragma unroll
    for (int off=32; off; off>>=1) v += __shfl_down(v, off, 64);
    if (lane == 0) red[pp][wid] = v;
  }
  __syncthreads();
  if (k < PB)
    out[pbase + k] = red[k][0]+red[k][1]+red[k][2]+red[k][3] + b3[0];
}

// ---------------------------------------------------------------------------
extern "C" void kernel_launch(void* const* d_in, const int* in_sizes, int n_in,
                              void* d_out, int out_size, void* d_ws, size_t ws_size,
                              hipStream_t stream)
{
  const float* cap   = (const float*)d_in[0];
  const float* bw    = (const float*)d_in[1];
  const int*   links = (const int*)  d_in[2];
  const float* pk    = (const float*)d_in[5];
  const float* prec  = (const float*)d_in[6];
  const float* pbias = (const float*)d_in[7];
  const float* lk    = (const float*)d_in[8];
  const float* lrec  = (const float*)d_in[9];
  const float* lbias = (const float*)d_in[10];
  const float* w1    = (const float*)d_in[11];
  const float* b1    = (const float*)d_in[12];
  const float* w2    = (const float*)d_in[13];
  const float* b2    = (const float*)d_in[14];
  const float* w3    = (const float*)d_in[15];
  const float* b3    = (const float*)d_in[16];
  float* out = (float*)d_out;

  char* ws = (char*)d_ws;
  float* path_state = (float*)(ws);                      // 16,777,216
  float* link_state = (float*)(ws + 16777216);           //  1,280,000
  float* m_link     = (float*)(ws + 18057216);           //  1,280,000
  float* xw         = (float*)(ws + 19337216);           //  3,840,000
  int*   counts     = (int*)  (ws + 23177216);           //     40,000
  int*   cursor     = (int*)  (ws + 23217216);           //     40,000
  int*   offsets    = (int*)  (ws + 23257216);           //     40,064
  int*   dest       = (int*)  (ws + 23297280);           //  4,194,304
  float* m_edge     = (float*)(ws + 27491584);           // 134,217,728  (end 161,709,312)

  const bool use_csr = (ws_size >= 161709312ull);

  init_states<<<N_PATHS_C/256, 256, 0, stream>>>(cap, bw, link_state, path_state);

  if (use_csr){
    hipMemsetAsync(counts, 0, 80000, stream);   // counts + cursor (contiguous)
    build_hist  <<<N_EDGES_C/256, 256, 0, stream>>>(links, counts);
    scan_offsets<<<1, 256, 0, stream>>>(counts, offsets);
    build_dest  <<<N_EDGES_C/256, 256, 0, stream>>>(links, offsets, cursor, dest);
    precompute_xw<<<(N_LINKS_C*96)/256, 256, 0, stream>>>(link_state, pk, pbias, xw);

    for (int t=0; t<T_C; t++){
      path_step3<<<N_PATHS_C/8, 256, 0, stream>>>(xw, links, dest, prec, pbias, path_state, m_edge);
      link_fused<<<(N_LINKS_C+7)/8, 256, 0, stream>>>(m_edge, offsets, lk, lrec, lbias, pk, pbias, link_state, xw);
    }
  } else {
    for (int t=0; t<T_C; t++){
      precompute_xw<<<(N_LINKS_C*96)/256, 256, 0, stream>>>(link_state, pk, pbias, xw);
      hipMemsetAsync(m_link, 0, (size_t)N_LINKS_C*D_C*sizeof(float), stream);
      path_step_atomic<<<N_PATHS_C/256, 256, 0, stream>>>(xw, links, prec, pbias, path_state, m_link);
      link_step<<<(N_LINKS_C+255)/256, 256, 0, stream>>>(m_link, lk, lrec, lbias, link_state);
    }
  }

  readout<<<N_PATHS_C/PB, 256, 0, stream>>>(path_state, w1, b1, w2, b2, w3, b3, out);
}

// Round 4
// 1650.517 us; speedup vs baseline: 9.3526x; 1.2904x over previous
//
#include <hip/hip_runtime.h>

#define N_LINKS_C 10000
#define N_PATHS_C 131072
#define N_EDGES_C (N_PATHS_C*8)
#define D_C 32
#define L_C 8
#define T_C 8
#define RU_C 256

typedef __attribute__((ext_vector_type(8))) short bf16x8;
typedef __attribute__((ext_vector_type(4))) float f32x4;

__device__ __forceinline__ float sigm(float x){
  return __builtin_amdgcn_rcpf(1.0f + __expf(-x));
}
__device__ __forceinline__ float tanh_fast(float x){
  float e = __expf(2.0f*x);
  return 1.0f - 2.0f*__builtin_amdgcn_rcpf(e + 1.0f);
}
__device__ __forceinline__ unsigned short f2bf(float f){
  unsigned int u = __float_as_uint(f);
  u = u + 0x7FFFu + ((u >> 16) & 1u);
  return (unsigned short)(u >> 16);
}

// ---------------------------------------------------------------------------
__global__ __launch_bounds__(256) void init_states(
    const float* __restrict__ cap, const float* __restrict__ bw,
    float* __restrict__ link_state, float* __restrict__ path_state)
{
  const int i = blockIdx.x*256 + threadIdx.x;
  if (i < N_PATHS_C){
    float4* r = reinterpret_cast<float4*>(path_state + (size_t)i*D_C);
    float4 z = make_float4(0.f,0.f,0.f,0.f);
    float4 f = make_float4(bw[i],0.f,0.f,0.f);
    r[0]=f;
    #pragma unroll
    for (int q=1;q<8;q++) r[q]=z;
  }
  if (i < N_LINKS_C){
    float4* r = reinterpret_cast<float4*>(link_state + (size_t)i*D_C);
    float4 z = make_float4(0.f,0.f,0.f,0.f);
    float4 f = make_float4(cap[i],0.f,0.f,0.f);
    r[0]=f;
    #pragma unroll
    for (int q=1;q<8;q++) r[q]=z;
  }
}

// ---------------------------------------------------------------------------
// CSR build
// ---------------------------------------------------------------------------
__global__ __launch_bounds__(256) void build_hist(
    const int* __restrict__ links, int* __restrict__ counts)
{
  const int e = blockIdx.x*256 + threadIdx.x;
  if (e < N_EDGES_C) atomicAdd(&counts[links[e]], 1);
}

__global__ __launch_bounds__(256) void scan_offsets(
    const int* __restrict__ counts, int* __restrict__ offsets)
{
  __shared__ int sums[256];
  const int t = threadIdx.x;
  const int base = t*40;
  int vals[40];
  int local = 0;
  #pragma unroll
  for (int k=0;k<40;k++){
    const int idx = base+k;
    const int c = (idx < N_LINKS_C) ? counts[idx] : 0;
    vals[k] = local; local += c;
  }
  sums[t] = local;
  __syncthreads();
  for (int d2=1; d2<256; d2<<=1){
    int v = (t>=d2) ? sums[t-d2] : 0;
    __syncthreads();
    sums[t] += v;
    __syncthreads();
  }
  const int off = sums[t] - local;
  #pragma unroll
  for (int k=0;k<40;k++){
    const int idx = base+k;
    if (idx < N_LINKS_C) offsets[idx] = off + vals[k];
  }
  if (t == 255) offsets[N_LINKS_C] = sums[255];
}

__global__ __launch_bounds__(256) void build_dest(
    const int* __restrict__ links, const int* __restrict__ offsets,
    int* __restrict__ cursor, int* __restrict__ dest)
{
  const int e = blockIdx.x*256 + threadIdx.x;
  if (e >= N_EDGES_C) return;
  const int l = links[e];
  dest[e] = offsets[l] + atomicAdd(&cursor[l], 1);
}

// ---------------------------------------------------------------------------
// Pack w1/w2 into per-MFMA-fragment bf16 layout.
// frag(nt) of w1: lane l, elem i -> w1[8*(l>>4)+i][nt*16 + (l&15)]
// frag(kt,nt) of w2: lane l, elem i -> w2[kt*32 + 8*(l>>4)+i][nt*16 + (l&15)]
// ---------------------------------------------------------------------------
__global__ __launch_bounds__(256) void pack_weights(
    const float* __restrict__ w1, const float* __restrict__ w2,
    unsigned short* __restrict__ w1p, unsigned short* __restrict__ w2p)
{
  const int t = blockIdx.x*256 + threadIdx.x;
  if (t < 1024){
    const int lane = t & 63;
    const int nt = t >> 6;
    const int g = lane >> 4, c = lane & 15;
    unsigned short tmp[8];
    #pragma unroll
    for (int i=0;i<8;i++)
      tmp[i] = f2bf(w1[(8*g + i)*RU_C + nt*16 + c]);
    *reinterpret_cast<uint4*>(w1p + (size_t)t*8) = *reinterpret_cast<uint4*>(tmp);
  } else if (t < 9216){
    const int u = t - 1024;
    const int lane = u & 63;
    const int fi = u >> 6;            // kt*16 + nt
    const int kt = fi >> 4, nt = fi & 15;
    const int g = lane >> 4, c = lane & 15;
    unsigned short tmp[8];
    #pragma unroll
    for (int i=0;i<8;i++)
      tmp[i] = f2bf(w2[(kt*32 + 8*g + i)*RU_C + nt*16 + c]);
    *reinterpret_cast<uint4*>(w2p + (size_t)u*8) = *reinterpret_cast<uint4*>(tmp);
  }
}

// ---------------------------------------------------------------------------
// xw[l][j] = link_state[l] . path_kernel[:,j] + path_bias[0][j]  (t=0 only)
// ---------------------------------------------------------------------------
__global__ __launch_bounds__(256) void precompute_xw(
    const float* __restrict__ link_state,
    const float* __restrict__ pk,
    const float* __restrict__ pbias,
    float* __restrict__ xw)
{
  const int tid = blockIdx.x*256 + threadIdx.x;
  if (tid >= N_LINKS_C*96) return;
  const int l = tid/96, j = tid - l*96;
  const float4* x4 = reinterpret_cast<const float4*>(link_state + (size_t)l*D_C);
  float acc = pbias[j];
  #pragma unroll
  for (int i4=0;i4<8;i4++){
    const float4 xv = x4[i4];
    acc = fmaf(xv.x, pk[(i4*4+0)*96+j],
          fmaf(xv.y, pk[(i4*4+1)*96+j],
          fmaf(xv.z, pk[(i4*4+2)*96+j],
          fmaf(xv.w, pk[(i4*4+3)*96+j], acc))));
  }
  xw[tid] = acc;
}

// ---------------------------------------------------------------------------
// Path GRU, half-wave per path, ALL gathers prefetched before the scan:
// the 8-step serial loop is pure LDS+VALU.
// ---------------------------------------------------------------------------
__global__ __launch_bounds__(256, 3) void path_step4(
    const float* __restrict__ xw,       // [N_LINKS][96], bias0 folded in
    const int*   __restrict__ links,    // [E]
    const int*   __restrict__ dest,     // [E]
    const float* __restrict__ prec,     // [32][96]
    const float* __restrict__ pbias,    // [2][96]
    float* __restrict__ path_state,     // [N_PATHS][32]
    float* __restrict__ m_edge)         // [E][32]
{
  __shared__ float hbuf[8][32];
  const int tid = threadIdx.x;
  const int wave = tid >> 6, lane = tid & 63;
  const int half = lane >> 5, d = lane & 31;
  const int slot = wave*2 + half;
  const int p = blockIdx.x*8 + slot;

  float wz[32], wr[32], wh[32];
  #pragma unroll
  for (int i=0;i<32;i++){
    wz[i] = prec[i*96 + d];
    wr[i] = prec[i*96 + 32 + d];
    wh[i] = prec[i*96 + 64 + d];
  }
  const float bz = pbias[96 + d];
  const float br = pbias[128 + d];
  const float bh = pbias[160 + d];

  const int ebase = p*8;
  const int4 La = reinterpret_cast<const int4*>(links + ebase)[0];
  const int4 Lb = reinterpret_cast<const int4*>(links + ebase)[1];
  const int4 Da = reinterpret_cast<const int4*>(dest + ebase)[0];
  const int4 Db = reinterpret_cast<const int4*>(dest + ebase)[1];
  const int ls[8] = {La.x,La.y,La.z,La.w,Lb.x,Lb.y,Lb.z,Lb.w};
  const int de[8] = {Da.x,Da.y,Da.z,Da.w,Db.x,Db.y,Db.z,Db.w};

  float xz_v[8], xr_v[8], xh_v[8];
  #pragma unroll
  for (int s=0;s<8;s++){
    const float* xr = xw + (size_t)ls[s]*96;
    xz_v[s] = xr[d];
    xr_v[s] = xr[32+d];
    xh_v[s] = xr[64+d];
  }

  float h = path_state[(size_t)p*D_C + d];
  hbuf[slot][d] = h;

  #pragma unroll
  for (int s=0;s<L_C;s++){
    float hz=bz, hr=br, hh=bh;
    const float4* hv4 = reinterpret_cast<const float4*>(hbuf[slot]);
    #pragma unroll
    for (int i4=0;i4<8;i4++){
      const float4 hq = hv4[i4];
      hz = fmaf(wz[i4*4+0],hq.x, fmaf(wz[i4*4+1],hq.y, fmaf(wz[i4*4+2],hq.z, fmaf(wz[i4*4+3],hq.w, hz))));
      hr = fmaf(wr[i4*4+0],hq.x, fmaf(wr[i4*4+1],hq.y, fmaf(wr[i4*4+2],hq.z, fmaf(wr[i4*4+3],hq.w, hr))));
      hh = fmaf(wh[i4*4+0],hq.x, fmaf(wh[i4*4+1],hq.y, fmaf(wh[i4*4+2],hq.z, fmaf(wh[i4*4+3],hq.w, hh))));
    }
    const float z = sigm(xz_v[s] + hz);
    const float r = sigm(xr_v[s] + hr);
    const float c = tanh_fast(xh_v[s] + r*hh);
    h = z*h + (1.0f - z)*c;

    __builtin_nontemporal_store(h, &m_edge[(size_t)de[s]*D_C + d]);
    hbuf[slot][d] = h;
  }
  __builtin_nontemporal_store(h, &path_state[(size_t)p*D_C + d]);
}

// ---------------------------------------------------------------------------
// Fused: segment-sum(m_edge) -> link GRU -> xw for next t-step.
// ---------------------------------------------------------------------------
__global__ __launch_bounds__(256) void link_fused(
    const float* __restrict__ m_edge,
    const int*   __restrict__ offsets,
    const float* __restrict__ lk,
    const float* __restrict__ lrec,
    const float* __restrict__ lbias,
    const float* __restrict__ pk,
    const float* __restrict__ pbias,
    float* __restrict__ link_state,
    float* __restrict__ xw)
{
  __shared__ float Kt[3072];
  __shared__ float Rt[3072];
  __shared__ float Pk[3072];
  __shared__ float xb[8][32];
  __shared__ float hb[8][32];
  const int tid = threadIdx.x;
  for (int k = tid; k < 3072; k += 256){
    Kt[k] = lk[k]; Rt[k] = lrec[k]; Pk[k] = pk[k];
  }
  __syncthreads();

  const int wave = tid >> 6, lane = tid & 63;
  const int half = lane >> 5, d = lane & 31;
  const int slot = wave*2 + half;
  const int l = blockIdx.x*8 + slot;
  if (l >= N_LINKS_C) return;

  const int s0 = offsets[l], s1 = offsets[l+1];
  float a0=0.f, a1=0.f, a2=0.f, a3=0.f;
  int i = s0;
  for (; i+3 < s1; i += 4){
    a0 += __builtin_nontemporal_load(&m_edge[(size_t)(i  )*D_C + d]);
    a1 += __builtin_nontemporal_load(&m_edge[(size_t)(i+1)*D_C + d]);
    a2 += __builtin_nontemporal_load(&m_edge[(size_t)(i+2)*D_C + d]);
    a3 += __builtin_nontemporal_load(&m_edge[(size_t)(i+3)*D_C + d]);
  }
  for (; i < s1; ++i)
    a0 += __builtin_nontemporal_load(&m_edge[(size_t)i*D_C + d]);
  const float x_d = (a0+a1)+(a2+a3);

  const float h_d = link_state[(size_t)l*D_C + d];
  xb[slot][d] = x_d;
  hb[slot][d] = h_d;

  float xz=lbias[d], xrg=lbias[32+d], xh=lbias[64+d];
  float hz=lbias[96+d], hr=lbias[128+d], hh=lbias[160+d];
  #pragma unroll
  for (int i2=0;i2<32;i2++){
    const float xv = xb[slot][i2];
    const float hv = hb[slot][i2];
    xz  = fmaf(Kt[i2*96      + d], xv, xz);
    xrg = fmaf(Kt[i2*96 + 32 + d], xv, xrg);
    xh  = fmaf(Kt[i2*96 + 64 + d], xv, xh);
    hz  = fmaf(Rt[i2*96      + d], hv, hz);
    hr  = fmaf(Rt[i2*96 + 32 + d], hv, hr);
    hh  = fmaf(Rt[i2*96 + 64 + d], hv, hh);
  }
  const float z = sigm(xz + hz);
  const float r = sigm(xrg + hr);
  const float c = tanh_fast(xh + r*hh);
  const float hn = z*h_d + (1.0f - z)*c;
  link_state[(size_t)l*D_C + d] = hn;
  hb[slot][d] = hn;

  float o0=pbias[d], o1=pbias[32+d], o2=pbias[64+d];
  #pragma unroll
  for (int i2=0;i2<32;i2++){
    const float hv = hb[slot][i2];
    o0 = fmaf(Pk[i2*96      + d], hv, o0);
    o1 = fmaf(Pk[i2*96 + 32 + d], hv, o1);
    o2 = fmaf(Pk[i2*96 + 64 + d], hv, o2);
  }
  xw[(size_t)l*96      + d] = o0;
  xw[(size_t)l*96 + 32 + d] = o1;
  xw[(size_t)l*96 + 64 + d] = o2;
}

// ---------------------------------------------------------------------------
// MFMA readout: 4 waves/block, 16 paths/wave.
// h1 = selu(ps@w1+b1) via 16 MFMA; transpose via LDS; h2 = relu(h1@w2+b2)
// via 8x16 MFMA; out = h2@w3 + b3 via per-lane dot + shfl reduce.
// ---------------------------------------------------------------------------
__global__ __launch_bounds__(256) void readout_mfma(
    const float* __restrict__ ps,
    const unsigned short* __restrict__ w1p,
    const float* __restrict__ b1,
    const unsigned short* __restrict__ w2p,
    const float* __restrict__ b2,
    const float* __restrict__ w3,
    const float* __restrict__ b3,
    float* __restrict__ out)
{
  __shared__ unsigned short h1lds[4][16][264];   // 528B row stride (bank-spread)
  const int tid = threadIdx.x;
  const int wave = tid >> 6, lane = tid & 63;
  const int g = lane >> 4, c = lane & 15;
  const int p0 = blockIdx.x*64 + wave*16;

  // ---- A-frag from path_state: A[m=c][k=8g+i]
  const float* arow = ps + (size_t)(p0 + c)*D_C + g*8;
  const float4 av0 = reinterpret_cast<const float4*>(arow)[0];
  const float4 av1 = reinterpret_cast<const float4*>(arow)[1];
  bf16x8 afrag;
  afrag[0]=(short)f2bf(av0.x); afrag[1]=(short)f2bf(av0.y);
  afrag[2]=(short)f2bf(av0.z); afrag[3]=(short)f2bf(av0.w);
  afrag[4]=(short)f2bf(av1.x); afrag[5]=(short)f2bf(av1.y);
  afrag[6]=(short)f2bf(av1.z); afrag[7]=(short)f2bf(av1.w);

  const f32x4 zero = {0.f,0.f,0.f,0.f};
  const bf16x8* w1f = reinterpret_cast<const bf16x8*>(w1p);
  const bf16x8* w2f = reinterpret_cast<const bf16x8*>(w2p);

  // ---- h1 GEMM: 16 N-tiles, K=32 in one MFMA each
  f32x4 acc[16];
  #pragma unroll
  for (int nt=0; nt<16; nt++){
    const bf16x8 bfrag = w1f[nt*64 + lane];
    acc[nt] = __builtin_amdgcn_mfma_f32_16x16x32_bf16(afrag, bfrag, zero, 0, 0, 0);
  }

  // ---- bias + selu + transposed store to LDS (row m=4g+r, col n=nt*16+c)
  #pragma unroll
  for (int nt=0; nt<16; nt++){
    const float bv = b1[nt*16 + c];
    #pragma unroll
    for (int r=0;r<4;r++){
      float v = acc[nt][r] + bv;
      v = (v > 0.f) ? 1.0507009873554805f*v
                    : 1.7580993408473766f*(__expf(v)-1.0f);
      h1lds[wave][4*g + r][nt*16 + c] = f2bf(v);
    }
  }

  // ---- h2 GEMM: A = h1[16][256] from LDS, 8 K-tiles x 16 N-tiles
  f32x4 acc2[16];
  #pragma unroll
  for (int nt=0; nt<16; nt++) acc2[nt] = zero;

  #pragma unroll
  for (int kt=0; kt<8; kt++){
    const bf16x8 af = *reinterpret_cast<const bf16x8*>(&h1lds[wave][c][kt*32 + g*8]);
    #pragma unroll
    for (int nt=0; nt<16; nt++){
      const bf16x8 bfrag = w2f[(kt*16 + nt)*64 + lane];
      acc2[nt] = __builtin_amdgcn_mfma_f32_16x16x32_bf16(af, bfrag, acc2[nt], 0, 0, 0);
    }
  }

  // ---- bias + relu + dot with w3, reduce over the 16 n-lanes
  float po0=0.f, po1=0.f, po2=0.f, po3=0.f;
  #pragma unroll
  for (int nt=0; nt<16; nt++){
    const float b2v = b2[nt*16 + c];
    const float w3v = w3[nt*16 + c];
    po0 = fmaf(fmaxf(acc2[nt][0] + b2v, 0.f), w3v, po0);
    po1 = fmaf(fmaxf(acc2[nt][1] + b2v, 0.f), w3v, po1);
    po2 = fmaf(fmaxf(acc2[nt][2] + b2v, 0.f), w3v, po2);
    po3 = fmaf(fmaxf(acc2[nt][3] + b2v, 0.f), w3v, po3);
  }
  #pragma unroll
  for (int mask=1; mask<16; mask<<=1){
    po0 += __shfl_xor(po0, mask, 64);
    po1 += __shfl_xor(po1, mask, 64);
    po2 += __shfl_xor(po2, mask, 64);
    po3 += __shfl_xor(po3, mask, 64);
  }
  if (c == 0){
    const float bb = b3[0];
    out[p0 + 4*g + 0] = po0 + bb;
    out[p0 + 4*g + 1] = po1 + bb;
    out[p0 + 4*g + 2] = po2 + bb;
    out[p0 + 4*g + 3] = po3 + bb;
  }
}

// ---------------------------------------------------------------------------
// Legacy kernels (no-CSR fallback)
// ---------------------------------------------------------------------------
__global__ __launch_bounds__(256, 4) void path_step_atomic(
    const float* __restrict__ xw, const int* __restrict__ links,
    const float* __restrict__ prec, const float* __restrict__ pbias,
    float* __restrict__ path_state, float* __restrict__ m_out)
{
  __shared__ float Rt[96*32];
  __shared__ float B1[96];
  for (int k = threadIdx.x; k < 96*32; k += 256)
    Rt[k] = prec[(k & 31)*96 + (k >> 5)];
  if (threadIdx.x < 96) B1[threadIdx.x] = pbias[96 + threadIdx.x];
  __syncthreads();

  const int p = blockIdx.x*256 + threadIdx.x;
  float h[32];
  {
    const float4* ps4 = reinterpret_cast<const float4*>(path_state + (size_t)p*D_C);
    #pragma unroll
    for (int q=0;q<8;q++){ float4 v = ps4[q]; h[q*4]=v.x; h[q*4+1]=v.y; h[q*4+2]=v.z; h[q*4+3]=v.w; }
  }
  #pragma unroll 1
  for (int s=0;s<L_C;s++){
    const int l = links[p*8+s];
    const float* xr = xw + (size_t)l*96;
    float hn[32];
    #pragma unroll
    for (int d0=0; d0<32; d0+=4){
      #pragma unroll
      for (int q=0;q<4;q++){
        const int d = d0+q;
        float hz = B1[d], hr = B1[32+d], hh = B1[64+d];
        const float4* rz = reinterpret_cast<const float4*>(Rt + d*32);
        const float4* rr = reinterpret_cast<const float4*>(Rt + (32+d)*32);
        const float4* rh = reinterpret_cast<const float4*>(Rt + (64+d)*32);
        #pragma unroll
        for (int i4=0;i4<8;i4++){
          const float4 a = rz[i4], b = rr[i4], c = rh[i4];
          hz = fmaf(a.x,h[i4*4+0],fmaf(a.y,h[i4*4+1],fmaf(a.z,h[i4*4+2],fmaf(a.w,h[i4*4+3],hz))));
          hr = fmaf(b.x,h[i4*4+0],fmaf(b.y,h[i4*4+1],fmaf(b.z,h[i4*4+2],fmaf(b.w,h[i4*4+3],hr))));
          hh = fmaf(c.x,h[i4*4+0],fmaf(c.y,h[i4*4+1],fmaf(c.z,h[i4*4+2],fmaf(c.w,h[i4*4+3],hh))));
        }
        const float z = sigm(xr[d] + hz);
        const float r = sigm(xr[32+d] + hr);
        const float c2 = tanh_fast(xr[64+d] + r*hh);
        hn[d] = z*h[d] + (1.0f - z)*c2;
      }
    }
    float* ml = m_out + (size_t)l*D_C;
    #pragma unroll
    for (int d=0; d<32; d++){ h[d]=hn[d]; atomicAdd(ml+d, h[d]); }
  }
  float4* ps4w = reinterpret_cast<float4*>(path_state + (size_t)p*D_C);
  #pragma unroll
  for (int q=0;q<8;q++){
    float4 v; v.x=h[q*4]; v.y=h[q*4+1]; v.z=h[q*4+2]; v.w=h[q*4+3];
    ps4w[q]=v;
  }
}

__global__ __launch_bounds__(256) void link_step(
    const float* __restrict__ m_link,
    const float* __restrict__ lk, const float* __restrict__ lrec,
    const float* __restrict__ lbias, float* __restrict__ link_state)
{
  __shared__ float Kt[96*32];
  __shared__ float Rt[96*32];
  __shared__ float B0[96], B1[96];
  for (int k = threadIdx.x; k < 96*32; k += 256){
    const int i = k & 31, j = k >> 5;
    Kt[k] = lk[i*96 + j];
    Rt[k] = lrec[i*96 + j];
  }
  if (threadIdx.x < 96){
    B0[threadIdx.x] = lbias[threadIdx.x];
    B1[threadIdx.x] = lbias[96 + threadIdx.x];
  }
  __syncthreads();
  const int l = blockIdx.x*256 + threadIdx.x;
  if (l >= N_LINKS_C) return;
  float x[32], h[32];
  {
    const float4* xv = reinterpret_cast<const float4*>(m_link + (size_t)l*D_C);
    const float4* hv = reinterpret_cast<const float4*>(link_state + (size_t)l*D_C);
    #pragma unroll
    for (int q=0;q<8;q++){
      float4 a = xv[q]; x[q*4]=a.x; x[q*4+1]=a.y; x[q*4+2]=a.z; x[q*4+3]=a.w;
      float4 b = hv[q]; h[q*4]=b.x; h[q*4+1]=b.y; h[q*4+2]=b.z; h[q*4+3]=b.w;
    }
  }
  float hn[32];
  #pragma unroll
  for (int d=0; d<32; d++){
    float xz=B0[d], xrg=B0[32+d], xh=B0[64+d];
    float hz=B1[d], hr=B1[32+d], hh=B1[64+d];
    const float4* kz = reinterpret_cast<const float4*>(Kt + d*32);
    const float4* kr = reinterpret_cast<const float4*>(Kt + (32+d)*32);
    const float4* kh = reinterpret_cast<const float4*>(Kt + (64+d)*32);
    const float4* rz = reinterpret_cast<const float4*>(Rt + d*32);
    const float4* rr = reinterpret_cast<const float4*>(Rt + (32+d)*32);
    const float4* rh = reinterpret_cast<const float4*>(Rt + (64+d)*32);
    #pragma unroll
    for (int i4=0;i4<8;i4++){
      const float4 a1 = kz[i4], a2 = kr[i4], a3 = kh[i4];
      const float4 b1 = rz[i4], b2 = rr[i4], b3 = rh[i4];
      xz  = fmaf(a1.x,x[i4*4+0],fmaf(a1.y,x[i4*4+1],fmaf(a1.z,x[i4*4+2],fmaf(a1.w,x[i4*4+3],xz))));
      xrg = fmaf(a2.x,x[i4*4+0],fmaf(a2.y,x[i4*4+1],fmaf(a2.z,x[i4*4+2],fmaf(a2.w,x[i4*4+3],xrg))));
      xh  = fmaf(a3.x,x[i4*4+0],fmaf(a3.y,x[i4*4+1],fmaf(a3.z,x[i4*4+2],fmaf(a3.w,x[i4*4+3],xh))));
      hz  = fmaf(b1.x,h[i4*4+0],fmaf(b1.y,h[i4*4+1],fmaf(b1.z,h[i4*4+2],fmaf(b1.w,h[i4*4+3],hz))));
      hr  = fmaf(b2.x,h[i4*4+0],fmaf(b2.y,h[i4*4+1],fmaf(b2.z,h[i4*4+2],fmaf(b2.w,h[i4*4+3],hr))));
      hh  = fmaf(b3.x,h[i4*4+0],fmaf(b3.y,h[i4*4+1],fmaf(b3.z,h[i4*4+2],fmaf(b3.w,h[i4*4+3],hh))));
    }
    const float z = sigm(xz + hz);
    const float r = sigm(xrg + hr);
    const float c2 = tanh_fast(xh + r*hh);
    hn[d] = z*h[d] + (1.0f - z)*c2;
  }
  float4* ov = reinterpret_cast<float4*>(link_state + (size_t)l*D_C);
  #pragma unroll
  for (int q=0;q<8;q++){
    float4 v; v.x=hn[q*4]; v.y=hn[q*4+1]; v.z=hn[q*4+2]; v.w=hn[q*4+3];
    ov[q]=v;
  }
}

#define PB 16
__global__ __launch_bounds__(256) void readout(
    const float* __restrict__ path_state,
    const float* __restrict__ w1, const float* __restrict__ b1,
    const float* __restrict__ w2, const float* __restrict__ b2,
    const float* __restrict__ w3, const float* __restrict__ b3,
    float* __restrict__ out)
{
  __shared__ float h1s[PB][RU_C];
  __shared__ float hin[PB][D_C];
  __shared__ float red[PB][4];
  const int k = threadIdx.x;
  const int pbase = blockIdx.x*PB;

  for (int idx = k; idx < PB*D_C; idx += 256)
    hin[idx>>5][idx&31] = path_state[(size_t)pbase*D_C + idx];
  __syncthreads();

  #pragma unroll 1
  for (int pp=0; pp<PB; pp++){
    float acc = b1[k];
    #pragma unroll
    for (int i=0;i<D_C;i++) acc = fmaf(hin[pp][i], w1[i*RU_C+k], acc);
    acc = (acc > 0.f) ? 1.0507009873554805f*acc
                      : 1.7580993408473766f*(__expf(acc)-1.0f);
    h1s[pp][k] = acc;
  }
  __syncthreads();

  float acc2[PB];
  #pragma unroll
  for (int pp=0;pp<PB;pp++) acc2[pp] = b2[k];

  #pragma unroll 1
  for (int j=0;j<RU_C;j+=4){
    const float wa = w2[(j+0)*RU_C+k];
    const float wb = w2[(j+1)*RU_C+k];
    const float wc = w2[(j+2)*RU_C+k];
    const float wd = w2[(j+3)*RU_C+k];
    #pragma unroll
    for (int pp=0;pp<PB;pp++){
      const float4 hv = *reinterpret_cast<const float4*>(&h1s[pp][j]);
      acc2[pp] = fmaf(hv.x,wa,fmaf(hv.y,wb,fmaf(hv.z,wc,fmaf(hv.w,wd,acc2[pp]))));
    }
  }

  const float w3k = w3[k];
  const int lane = k & 63, wid = k >> 6;
  #pragma unroll
  for (int pp=0;pp<PB;pp++){
    float v = fmaxf(acc2[pp], 0.f) * w3k;
    #pragma unroll
    for (int off=32; off; off>>=1) v += __shfl_down(v, off, 64);
    if (lane == 0) red[pp][wid] = v;
  }
  __syncthreads();
  if (k < PB)
    out[pbase + k] = red[k][0]+red[k][1]+red[k][2]+red[k][3] + b3[0];
}

// ---------------------------------------------------------------------------
extern "C" void kernel_launch(void* const* d_in, const int* in_sizes, int n_in,
                              void* d_out, int out_size, void* d_ws, size_t ws_size,
                              hipStream_t stream)
{
  const float* cap   = (const float*)d_in[0];
  const float* bw    = (const float*)d_in[1];
  const int*   links = (const int*)  d_in[2];
  const float* pk    = (const float*)d_in[5];
  const float* prec  = (const float*)d_in[6];
  const float* pbias = (const float*)d_in[7];
  const float* lk    = (const float*)d_in[8];
  const float* lrec  = (const float*)d_in[9];
  const float* lbias = (const float*)d_in[10];
  const float* w1    = (const float*)d_in[11];
  const float* b1    = (const float*)d_in[12];
  const float* w2    = (const float*)d_in[13];
  const float* b2    = (const float*)d_in[14];
  const float* w3    = (const float*)d_in[15];
  const float* b3    = (const float*)d_in[16];
  float* out = (float*)d_out;

  char* ws = (char*)d_ws;
  float* path_state = (float*)(ws);                      // 16,777,216
  float* link_state = (float*)(ws + 16777216);           //  1,280,000
  float* m_link     = (float*)(ws + 18057216);           //  1,280,000 (fallback only)
  unsigned short* w1p = (unsigned short*)(ws + 18057216);//     16,384 (CSR path reuse)
  unsigned short* w2p = (unsigned short*)(ws + 18073600);//    131,072
  float* xw         = (float*)(ws + 19337216);           //  3,840,000
  int*   counts     = (int*)  (ws + 23177216);           //     40,000
  int*   cursor     = (int*)  (ws + 23217216);           //     40,000
  int*   offsets    = (int*)  (ws + 23257216);           //     40,064
  int*   dest       = (int*)  (ws + 23297280);           //  4,194,304
  float* m_edge     = (float*)(ws + 27491584);           // 134,217,728 (end 161,709,312)

  const bool use_csr = (ws_size >= 161709312ull);

  init_states<<<N_PATHS_C/256, 256, 0, stream>>>(cap, bw, link_state, path_state);

  if (use_csr){
    hipMemsetAsync(counts, 0, 80000, stream);   // counts + cursor
    build_hist  <<<N_EDGES_C/256, 256, 0, stream>>>(links, counts);
    scan_offsets<<<1, 256, 0, stream>>>(counts, offsets);
    build_dest  <<<N_EDGES_C/256, 256, 0, stream>>>(links, offsets, cursor, dest);
    pack_weights<<<36, 256, 0, stream>>>(w1, w2, w1p, w2p);
    precompute_xw<<<(N_LINKS_C*96)/256, 256, 0, stream>>>(link_state, pk, pbias, xw);

    for (int t=0; t<T_C; t++){
      path_step4<<<N_PATHS_C/8, 256, 0, stream>>>(xw, links, dest, prec, pbias, path_state, m_edge);
      link_fused<<<(N_LINKS_C+7)/8, 256, 0, stream>>>(m_edge, offsets, lk, lrec, lbias, pk, pbias, link_state, xw);
    }
    readout_mfma<<<N_PATHS_C/64, 256, 0, stream>>>(path_state, w1p, b1, w2p, b2, w3, b3, out);
  } else {
    for (int t=0; t<T_C; t++){
      precompute_xw<<<(N_LINKS_C*96)/256, 256, 0, stream>>>(link_state, pk, pbias, xw);
      hipMemsetAsync(m_link, 0, (size_t)N_LINKS_C*D_C*sizeof(float), stream);
      path_step_atomic<<<N_PATHS_C/256, 256, 0, stream>>>(xw, links, prec, pbias, path_state, m_link);
      link_step<<<(N_LINKS_C+255)/256, 256, 0, stream>>>(m_link, lk, lrec, lbias, link_state);
    }
    readout<<<N_PATHS_C/PB, 256, 0, stream>>>(path_state, w1, b1, w2, b2, w3, b3, out);
  }
}